// Round 5
// baseline (222.258 us; speedup 1.0000x reference)
//
#include <hip/hip_runtime.h>
#include <math.h>

// FitzHugh-Nagumo RK4, one thread per trajectory. 2047 sequential steps;
// 64 waves (1/CU) -> wall time = per-step SIMD issue time. The SIMD datapath
// is 32 FP32 lanes/cy, so a wave64 f32 op = 2 cy regardless of packing
// (v_pk_fma_f32 = 4 cy: no issue-BW gain, plus swizzle movs -> round 3's gap).
// This version minimizes scalar FP32 op COUNT:
//   - y-substeps are linear -> coefficients pre-folded (y2: 2 ops).
//   - xn/yn via RK4 identity with s4 and all constants folded into
//     per-term coefficients: xn 6 ops, yn 5 ops, no k1..k4.
// Total: 36 VALU/step (~72 cy issue floor) + 1 store + 1 addr inc.
// Critical x-chain: x->p1->q1->x2->...->q4->xn = 13 deps * ~4cy = 52cy < issue.

__global__ __launch_bounds__(64) void fhn_rk4_kernel(
    const float* __restrict__ x0, const float* __restrict__ y0,
    const float* __restrict__ pa, const float* __restrict__ pb,
    const float* __restrict__ pc, float2* __restrict__ out,
    int B, int num_steps)
{
    const int i = blockIdx.x * 64 + threadIdx.x;
    if (i >= B) return;

    const float a = pa[0];
    const float b = pb[0];
    const float c = pc[0];

    const float dt   = 0.1f;
    const float h    = 0.05f;
    const float dt6  = 0.1f / 6.0f;
    const float c3   = 1.0f / 3.0f;

    // x-side constants
    const float hc     = h * c;
    const float mhcc3  = -(h * c * c3);
    const float dc     = dt * c;
    const float mdcc3  = -(dt * c * c3);
    const float d6c    = dt6 * c;
    const float md6cc3 = -(dt6 * c * c3);
    const float E4x    = c3 + d6c;          // coeff of x4 in xn (s4 folded)

    // y-side constants (f_y is linear: g = nic*x + nicb*y + anc)
    const float nic   = -1.0f / c;
    const float nicb  = -b / c;
    const float anc   = a / c;
    const float A1    = 1.0f + h * nicb;    // y2 = A1*y + B1*x + C1
    const float B1    = h * nic;
    const float C1    = h * anc;
    const float hnicb = h * nicb;
    const float dnic  = dt * nic;
    const float dnicb = dt * nicb;
    const float danc  = dt * anc;
    const float d6nic = dt6 * nic;
    const float d6anc = dt6 * anc;
    const float E4y   = c3 + dt6 * nicb;    // coeff of y4 in yn (k4y folded)

    float x = x0[i];
    float y = y0[i];

    float2* o = out + i;
    *o = make_float2(x, y);
    o += B;

#pragma unroll 4
    for (int s = 1; s < num_steps; ++s, o += B) {
        // y2 — linear, dep only on (x,y): computed in parallel with x-chain
        const float y2 = fmaf(B1, x, fmaf(A1, y, C1));

        // x stage 1
        const float s1 = x + y;
        const float p1 = x * x;
        const float q1 = p1 * x;
        const float x2 = fmaf(mhcc3, q1, fmaf(hc, s1, x));

        // y3 (dep x2 arrives late, single fma after)
        const float yha = y + C1;
        const float y3 = fmaf(B1, x2, fmaf(hnicb, y2, yha));

        // x stage 2
        const float s2 = x2 + y2;
        const float p2 = x2 * x2;
        const float q2 = p2 * x2;
        const float x3 = fmaf(mhcc3, q2, fmaf(hc, s2, x));

        // y4
        const float yda = y + danc;
        const float y4 = fmaf(dnic, x3, fmaf(dnicb, y3, yda));

        // x stage 3 (full dt)
        const float s3 = x3 + y3;
        const float p3 = x3 * x3;
        const float q3 = p3 * x3;
        const float x4 = fmaf(mdcc3, q3, fmaf(dc, s3, x));

        // stage 4 cubic only (s4 folded into E4x / d6c*y4 terms)
        const float p4 = x4 * x4;
        const float q4 = p4 * x4;

        // xn = -x/3 + x2/3 + 2/3 x3 + E4x*x4 + d6c*y4 - d6cc3*q4
        float vx = x * (-c3);
        vx = fmaf(c3, x2, vx);
        vx = fmaf(2.0f * c3, x3, vx);
        vx = fmaf(E4x, x4, vx);
        vx = fmaf(d6c, y4, vx);
        x = fmaf(md6cc3, q4, vx);

        // yn = -y/3 + y2/3 + 2/3 y3 + E4y*y4 + d6nic*x4 + d6anc
        float wy = fmaf(-c3, y, d6anc);
        wy = fmaf(c3, y2, wy);
        wy = fmaf(2.0f * c3, y3, wy);
        wy = fmaf(E4y, y4, wy);
        y = fmaf(d6nic, x4, wy);

        *o = make_float2(x, y);
    }
}

extern "C" void kernel_launch(void* const* d_in, const int* in_sizes, int n_in,
                              void* d_out, int out_size, void* d_ws, size_t ws_size,
                              hipStream_t stream) {
    const float* x0 = (const float*)d_in[0];
    const float* y0 = (const float*)d_in[1];
    const float* pa = (const float*)d_in[2];
    const float* pb = (const float*)d_in[3];
    const float* pc = (const float*)d_in[4];
    const int B = in_sizes[0];
    const int num_steps = out_size / (2 * B);

    float2* out = (float2*)d_out;

    const int block = 64;
    const int grid = (B + block - 1) / block;
    fhn_rk4_kernel<<<grid, block, 0, stream>>>(x0, y0, pa, pb, pc, out, B, num_steps);
}